// Round 1
// baseline (805.066 us; speedup 1.0000x reference)
//
#include <hip/hip_runtime.h>
#include <hip/hip_bf16.h>

// Problem constants (from reference)
#define BB   32
#define TT   24
#define BT   768      // B*T
#define NN   512
#define DIN  64
#define DOUT 2
#define HID  128
#define EMB  16
#define SLOPE 0.01f

// ---------------- workspace layout (bytes) ----------------
// wspa  : [512,128,128] f32 = 33,554,432
// wtem  : [768,128,128] f32 = 50,331,648
// bspa  : [512,128]     f32 =    262,144
// btem  : [768,128]     f32 =    393,216
// h2    : [768,512,128] f32 (201,326,592) or bf16 (100,663,296)
static const size_t OFF_WTEM = 33554432;
static const size_t OFF_BSPA = 83886080;
static const size_t OFF_BTEM = 84148224;
static const size_t OFF_H2   = 84541440;

__device__ __forceinline__ float h2_load(const float* p) { return *p; }
__device__ __forceinline__ float h2_load(const __hip_bfloat16* p) { return __bfloat162float(*p); }
__device__ __forceinline__ void  h2_store(float* p, float v) { *p = v; }
__device__ __forceinline__ void  h2_store(__hip_bfloat16* p, float v) { *p = __float2bfloat16(v); }

// ---------------------------------------------------------------------------
// genW: out[n][i][o] = sum_d emb[n][d] * pool[d][i][o]
// grid: (16 io-blocks of 1024 cols, cnt/64 n-blocks), 256 threads.
// Each thread owns 4 consecutive io columns (pool slice in 64 VGPRs),
// loops 64 n rows (emb rows broadcast from LDS). Pool read exactly once
// per n-block -> ~12 MB total L2 traffic instead of ~1.3 GB naive.
// ---------------------------------------------------------------------------
__global__ __launch_bounds__(256)
void k_genw(const float* __restrict__ pool, const float* __restrict__ emb,
            float* __restrict__ outw)
{
    const int t  = threadIdx.x;
    const int nb = blockIdx.y;
    __shared__ float sEmb[64 * EMB];
    #pragma unroll
    for (int c = 0; c < 4; ++c) {
        int idx = c * 256 + t;                    // 1024 = 64*16
        sEmb[idx] = emb[nb * 64 * EMB + idx];
    }
    __syncthreads();
    const int ioq = blockIdx.x * 256 + t;         // float4 column index
    float4 p[EMB];
    #pragma unroll
    for (int d = 0; d < EMB; ++d)
        p[d] = ((const float4*)pool)[d * 4096 + ioq];
    for (int nn = 0; nn < 64; ++nn) {
        float4 a = make_float4(0.f, 0.f, 0.f, 0.f);
        #pragma unroll
        for (int d = 0; d < EMB; ++d) {
            float e = sEmb[nn * EMB + d];
            a.x += e * p[d].x; a.y += e * p[d].y;
            a.z += e * p[d].z; a.w += e * p[d].w;
        }
        ((float4*)outw)[(size_t)(nb * 64 + nn) * 4096 + ioq] = a;
    }
}

// genB: out[n][o] = sum_d emb[n][d] * bpool[d][o]   (tiny)
__global__ __launch_bounds__(256)
void k_genb(const float* __restrict__ bpool, const float* __restrict__ emb,
            float* __restrict__ outb, int cnt)
{
    int q = blockIdx.x * blockDim.x + threadIdx.x;  // float4 index
    if (q >= cnt * 32) return;
    int n = q >> 5, oq = q & 31;
    float4 a = make_float4(0.f, 0.f, 0.f, 0.f);
    #pragma unroll
    for (int d = 0; d < EMB; ++d) {
        float e = emb[n * EMB + d];
        float4 bp = ((const float4*)bpool)[d * 32 + oq];
        a.x += e * bp.x; a.y += e * bp.y; a.z += e * bp.z; a.w += e * bp.w;
    }
    ((float4*)outb)[q] = a;
}

// ---------------------------------------------------------------------------
// k_spatial: h2[R][n][:] = leaky( (eb[R][n]@W1 + b1) @ Wspa[n] + bspa[n] )
// grid (512 n, 24 bt-tiles of 32 rows), 256 threads.
// Phase1: h1T[128][32] built in LDS (per-thread 4x4 tile vs LDS W1).
// Phase2: 2 x 64-col halves of Wspa staged in LDS (region aliases the
//         phase-1 W1/ebT region -> 60 KB static LDS total, 2 blocks/CU).
// Per-thread 4x2 outer-product accumulation; leaky + store to h2.
// ---------------------------------------------------------------------------
template <typename TH2>
__global__ __launch_bounds__(256)
void k_spatial(const float* __restrict__ eb, const float* __restrict__ W1g,
               const float* __restrict__ b1, const float* __restrict__ wspa,
               const float* __restrict__ bspa, TH2* __restrict__ h2)
{
    const int n  = blockIdx.x;
    const int R0 = blockIdx.y * 32;
    const int t  = threadIdx.x;
    const int rq = t >> 5;          // 0..7  -> rows rq*4..rq*4+3
    const int cq = t & 31;          // 0..31 -> cols (phase-dependent)

    __shared__ float sH1T[HID * 36];        // h1 transposed [i][r], pad 36
    __shared__ float sB1[HID];
    __shared__ float sBs[HID];
    __shared__ float sU[DIN * HID + DIN * 36]; // union: {W1 + ebT} / {Wspa half}
    float* sW1  = sU;
    float* sEbT = sU + DIN * HID;
    float* sWh  = sU;                       // phase2 alias (128*64 floats)

    // ---- stage W1 (8192 f), biases, ebT (32 rows x 64 k, transposed) ----
    {
        const float4* g = (const float4*)W1g;
        float4* s = (float4*)sW1;
        #pragma unroll
        for (int c = 0; c < 8; ++c) s[c * 256 + t] = g[c * 256 + t];
    }
    if (t < HID) { sB1[t] = b1[t]; sBs[t] = bspa[n * HID + t]; }
    #pragma unroll
    for (int c = 0; c < 8; ++c) {
        int idx = c * 256 + t;              // 2048 = 32*64
        int r = idx >> 6, k = idx & 63;
        sEbT[k * 36 + r] = eb[((size_t)(R0 + r) * NN + n) * DIN + k];
    }
    __syncthreads();

    // ---- phase 1: h1 = eb @ W1 + b1, stored transposed ----
    float acc[4][4];
    #pragma unroll
    for (int a = 0; a < 4; ++a)
        #pragma unroll
        for (int b = 0; b < 4; ++b) acc[a][b] = 0.f;
    #pragma unroll 16
    for (int k = 0; k < DIN; ++k) {
        float4 av = *(const float4*)(sEbT + k * 36 + rq * 4);
        float4 bv = *(const float4*)(sW1 + k * HID + cq * 4);
        acc[0][0] += av.x * bv.x; acc[0][1] += av.x * bv.y; acc[0][2] += av.x * bv.z; acc[0][3] += av.x * bv.w;
        acc[1][0] += av.y * bv.x; acc[1][1] += av.y * bv.y; acc[1][2] += av.y * bv.z; acc[1][3] += av.y * bv.w;
        acc[2][0] += av.z * bv.x; acc[2][1] += av.z * bv.y; acc[2][2] += av.z * bv.z; acc[2][3] += av.z * bv.w;
        acc[3][0] += av.w * bv.x; acc[3][1] += av.w * bv.y; acc[3][2] += av.w * bv.z; acc[3][3] += av.w * bv.w;
    }
    #pragma unroll
    for (int jj = 0; jj < 4; ++jj) {
        float bb = sB1[cq * 4 + jj];
        #pragma unroll
        for (int rr = 0; rr < 4; ++rr)
            sH1T[(cq * 4 + jj) * 36 + rq * 4 + rr] = acc[rr][jj] + bb;
    }

    // ---- phase 2: h2 = leaky(h1 @ Wspa + bspa), two 64-col halves ----
    for (int oh = 0; oh < 2; ++oh) {
        __syncthreads();   // phase-1 region done / protect sWh from prev readers
        #pragma unroll
        for (int c = 0; c < 8; ++c) {
            int idx = c * 256 + t;          // 2048 float4 = 8192 f
            int i = idx >> 4, col4 = (idx & 15) * 4;
            *(float4*)(sWh + i * 64 + col4) =
                *(const float4*)(wspa + (size_t)n * 16384 + i * HID + oh * 64 + col4);
        }
        __syncthreads();
        float acc2[4][2] = {{0.f, 0.f}, {0.f, 0.f}, {0.f, 0.f}, {0.f, 0.f}};
        #pragma unroll 16
        for (int i = 0; i < HID; ++i) {
            float4 av = *(const float4*)(sH1T + i * 36 + rq * 4);
            float2 bv = *(const float2*)(sWh + i * 64 + cq * 2);
            acc2[0][0] += av.x * bv.x; acc2[0][1] += av.x * bv.y;
            acc2[1][0] += av.y * bv.x; acc2[1][1] += av.y * bv.y;
            acc2[2][0] += av.z * bv.x; acc2[2][1] += av.z * bv.y;
            acc2[3][0] += av.w * bv.x; acc2[3][1] += av.w * bv.y;
        }
        #pragma unroll
        for (int rr = 0; rr < 4; ++rr) {
            int R = R0 + rq * 4 + rr;
            size_t base = ((size_t)R * NN + n) * HID + oh * 64 + cq * 2;
            #pragma unroll
            for (int oo = 0; oo < 2; ++oo) {
                float v = acc2[rr][oo] + sBs[oh * 64 + cq * 2 + oo];
                v = (v >= 0.f) ? v : SLOPE * v;
                h2_store(h2 + base + oo, v);
            }
        }
    }
}

// ---------------------------------------------------------------------------
// k_temporal: logits[R][n][:] = leaky(h2[R][n]@Wtem[R] + btem[R]) @ W3 + b3
// grid 768 blocks (one per R=b*T+t), 256 threads, 16 n-tiles of 32 rows.
// Same 2-half GEMM; epilogue fuses bias+leaky+W3 with a 32-lane shfl reduce.
// ---------------------------------------------------------------------------
template <typename TH2>
__global__ __launch_bounds__(256)
void k_temporal(const TH2* __restrict__ h2, const float* __restrict__ wtem,
                const float* __restrict__ btem, const float* __restrict__ W3,
                const float* __restrict__ b3, float* __restrict__ out)
{
    const int R  = blockIdx.x;
    const int t  = threadIdx.x;
    const int rq = t >> 5;
    const int oq = t & 31;

    __shared__ float sH2T[HID * 36];
    __shared__ float sWh[HID * 64];
    __shared__ float sBt[HID];
    __shared__ float sW3[HID * DOUT];

    if (t < HID) sBt[t] = btem[R * HID + t];
    sW3[t] = W3[t & (HID * DOUT - 1)];       // 256 threads cover 256 entries
    const float b30 = b3[0], b31 = b3[1];

    for (int nt = 0; nt < 16; ++nt) {
        __syncthreads();                      // protect sH2T from prev readers
        #pragma unroll
        for (int c = 0; c < 16; ++c) {
            int idx = c * 256 + t;            // 4096 = 32*128
            int r = idx >> 7, i = idx & 127;
            sH2T[i * 36 + r] = h2_load(h2 + ((size_t)R * NN + nt * 32 + r) * HID + i);
        }
        float pl[4][2] = {{0.f, 0.f}, {0.f, 0.f}, {0.f, 0.f}, {0.f, 0.f}};
        for (int oh = 0; oh < 2; ++oh) {
            __syncthreads();                  // sH2T ready / protect sWh
            #pragma unroll
            for (int c = 0; c < 8; ++c) {
                int idx = c * 256 + t;
                int i = idx >> 4, col4 = (idx & 15) * 4;
                *(float4*)(sWh + i * 64 + col4) =
                    *(const float4*)(wtem + (size_t)R * 16384 + i * HID + oh * 64 + col4);
            }
            __syncthreads();
            float acc[4][2] = {{0.f, 0.f}, {0.f, 0.f}, {0.f, 0.f}, {0.f, 0.f}};
            #pragma unroll 16
            for (int i = 0; i < HID; ++i) {
                float4 av = *(const float4*)(sH2T + i * 36 + rq * 4);
                float2 bv = *(const float2*)(sWh + i * 64 + oq * 2);
                acc[0][0] += av.x * bv.x; acc[0][1] += av.x * bv.y;
                acc[1][0] += av.y * bv.x; acc[1][1] += av.y * bv.y;
                acc[2][0] += av.z * bv.x; acc[2][1] += av.z * bv.y;
                acc[3][0] += av.w * bv.x; acc[3][1] += av.w * bv.y;
            }
            #pragma unroll
            for (int rr = 0; rr < 4; ++rr) {
                #pragma unroll
                for (int oo = 0; oo < 2; ++oo) {
                    int o = oh * 64 + oq * 2 + oo;
                    float v = acc[rr][oo] + sBt[o];
                    v = (v >= 0.f) ? v : SLOPE * v;
                    pl[rr][0] += v * sW3[o * 2];
                    pl[rr][1] += v * sW3[o * 2 + 1];
                }
            }
        }
        // reduce over oq (lanes 0..31 / 32..63 each hold one rq)
        #pragma unroll
        for (int m = 16; m >= 1; m >>= 1) {
            #pragma unroll
            for (int rr = 0; rr < 4; ++rr) {
                pl[rr][0] += __shfl_xor(pl[rr][0], m, 64);
                pl[rr][1] += __shfl_xor(pl[rr][1], m, 64);
            }
        }
        if (oq == 0) {
            #pragma unroll
            for (int rr = 0; rr < 4; ++rr) {
                int nn = nt * 32 + rq * 4 + rr;
                *(float2*)(out + ((size_t)R * NN + nn) * DOUT) =
                    make_float2(pl[rr][0] + b30, pl[rr][1] + b31);
            }
        }
    }
}

extern "C" void kernel_launch(void* const* d_in, const int* in_sizes, int n_in,
                              void* d_out, int out_size, void* d_ws, size_t ws_size,
                              hipStream_t stream) {
    const float* eb        = (const float*)d_in[0];
    const float* time_eb   = (const float*)d_in[1];
    const float* node_eb   = (const float*)d_in[2];
    const float* W1        = (const float*)d_in[3];
    const float* b1        = (const float*)d_in[4];
    const float* W3        = (const float*)d_in[5];
    const float* b3        = (const float*)d_in[6];
    const float* pool_spa  = (const float*)d_in[7];
    const float* bpool_spa = (const float*)d_in[8];
    const float* pool_tem  = (const float*)d_in[9];
    const float* bpool_tem = (const float*)d_in[10];
    float* out = (float*)d_out;

    char* ws = (char*)d_ws;
    float* wspa = (float*)ws;
    float* wtem = (float*)(ws + OFF_WTEM);
    float* bspa = (float*)(ws + OFF_BSPA);
    float* btem = (float*)(ws + OFF_BTEM);
    void*  h2   = (void*)(ws + OFF_H2);
    const bool h2_f32 = ws_size >= OFF_H2 + (size_t)BT * NN * HID * sizeof(float);

    // hyper-weight / bias generation
    k_genw<<<dim3(16, NN / 64), 256, 0, stream>>>(pool_spa, node_eb, wspa);
    k_genw<<<dim3(16, BT / 64), 256, 0, stream>>>(pool_tem, time_eb, wtem);
    k_genb<<<dim3((NN * 32 + 255) / 256), 256, 0, stream>>>(bpool_spa, node_eb, bspa, NN);
    k_genb<<<dim3((BT * 32 + 255) / 256), 256, 0, stream>>>(bpool_tem, time_eb, btem, BT);

    if (h2_f32) {
        k_spatial<float><<<dim3(NN, BT / 32), 256, 0, stream>>>(
            eb, W1, b1, wspa, bspa, (float*)h2);
        k_temporal<float><<<dim3(BT), 256, 0, stream>>>(
            (const float*)h2, wtem, btem, W3, b3, out);
    } else {
        k_spatial<__hip_bfloat16><<<dim3(NN, BT / 32), 256, 0, stream>>>(
            eb, W1, b1, wspa, bspa, (__hip_bfloat16*)h2);
        k_temporal<__hip_bfloat16><<<dim3(BT), 256, 0, stream>>>(
            (const __hip_bfloat16*)h2, wtem, btem, W3, b3, out);
    }
}

// Round 2
// 248.284 us; speedup vs baseline: 3.2425x; 3.2425x over previous
//
#include <hip/hip_runtime.h>
#include <hip/hip_bf16.h>
#include <stdint.h>

// Problem constants
#define BT   768
#define NN   512
#define DIN  64
#define HID  128
#define EMB  16
#define SLOPE 0.01f

typedef __attribute__((ext_vector_type(8))) short bf16x8;   // 8 bf16 (4 VGPRs)
typedef __attribute__((ext_vector_type(4))) float f32x4;    // MFMA C/D frag
typedef __attribute__((ext_vector_type(4))) short short4v;

__device__ __forceinline__ short f2bf(float f) {            // fp32 -> bf16 RNE
    uint32_t u = __float_as_uint(f);
    u += 0x7fff + ((u >> 16) & 1);
    return (short)(u >> 16);
}
__device__ __forceinline__ float bf2f(short s) {
    return __uint_as_float(((uint32_t)(unsigned short)s) << 16);
}

// ---------------- workspace layout (bytes) ----------------
// wspa_t [512][128 o][128 i] bf16 ; wtem_t [768][128][128] bf16
// bspa/btem fp32 ; pool_t (bf16, [d][o][i]) ; W1T bf16 [o][k] ; h2 bf16 [R][n][o]
static const size_t OFF_WSPA = 0;
static const size_t OFF_WTEM = 16777216;
static const size_t OFF_BSPA = 41943040;
static const size_t OFF_BTEM = 42205184;
static const size_t OFF_PTS  = 42598400;
static const size_t OFF_PTT  = 43122688;
static const size_t OFF_W1T  = 43646976;
static const size_t OFF_H2   = 43663360;   // end 144,326,656

// ---------------------------------------------------------------------------
// k_prep: blocks 0..63 transpose pool_spa [d][i][o]->bf16 [d][o][i] (LDS tile),
//         blocks 64..127 same for pool_tem, block 128 builds W1T bf16 [o][k].
// ---------------------------------------------------------------------------
__global__ __launch_bounds__(256)
void k_prep(const float* __restrict__ pool_spa, const float* __restrict__ pool_tem,
            const float* __restrict__ W1, short* __restrict__ pts,
            short* __restrict__ ptt, short* __restrict__ w1t)
{
    const int b = blockIdx.x, t = threadIdx.x;
    if (b == 128) {
        int o = t >> 1, kh = (t & 1) * 32;
        for (int k = 0; k < 32; ++k)
            w1t[o * 64 + kh + k] = f2bf(W1[(kh + k) * HID + o]);
        return;
    }
    const float* pool = (b < 64) ? pool_spa : pool_tem;
    short* outp = (b < 64) ? pts : ptt;
    const int bb = b & 63;
    const int d = bb >> 2, o0 = (bb & 3) * 32;
    __shared__ short s[32 * 136];
    #pragma unroll
    for (int c = 0; c < 16; ++c) {
        int e = c * 256 + t;
        int i = e >> 5, oo = e & 31;
        s[oo * 136 + i] = f2bf(pool[(d * HID + i) * HID + o0 + oo]);
    }
    __syncthreads();
    #pragma unroll
    for (int c = 0; c < 8; ++c) {
        int e = c * 256 + t;
        int oo = e >> 6, ii = (e & 63) * 2;
        uint32_t lo = (unsigned short)s[oo * 136 + ii];
        uint32_t hi = (unsigned short)s[oo * 136 + ii + 1];
        ((uint32_t*)outp)[((d * HID + o0 + oo) * HID + ii) >> 1] = lo | (hi << 16);
    }
}

// ---------------------------------------------------------------------------
// k_genw: out_t[n][o][i] = sum_d emb[n][d] * pool_t[d][o][i]   (bf16 out)
// Pool slice lives in 64 VGPRs per thread; read ONCE per 64-n block.
// grid (16 col-blocks, 8 spa + 12 tem n-blocks).
// ---------------------------------------------------------------------------
__global__ __launch_bounds__(256)
void k_genw(const short* __restrict__ pts, const short* __restrict__ ptt,
            const float* __restrict__ node_eb, const float* __restrict__ time_eb,
            short* __restrict__ wspa, short* __restrict__ wtem)
{
    const int t = threadIdx.x;
    const bool spa = blockIdx.y < 8;
    const int nb = spa ? blockIdx.y : blockIdx.y - 8;
    const short* pool = spa ? pts : ptt;
    const float* emb = spa ? node_eb : time_eb;
    short* outp = spa ? wspa : wtem;
    __shared__ float sEmb[64 * EMB];
    #pragma unroll
    for (int c = 0; c < 4; ++c) {
        int idx = c * 256 + t;
        sEmb[idx] = emb[nb * 64 * EMB + idx];
    }
    __syncthreads();
    const int cq = blockIdx.x * 256 + t;      // group of 4 bf16 cols
    float4 p[EMB];
    #pragma unroll
    for (int d = 0; d < EMB; ++d) {
        short4v v = ((const short4v*)pool)[d * 4096 + cq];
        p[d] = make_float4(bf2f(v.x), bf2f(v.y), bf2f(v.z), bf2f(v.w));
    }
    for (int nn = 0; nn < 64; ++nn) {
        float4 a = make_float4(0.f, 0.f, 0.f, 0.f);
        #pragma unroll
        for (int d = 0; d < EMB; ++d) {
            float e = sEmb[nn * EMB + d];
            a.x += e * p[d].x; a.y += e * p[d].y;
            a.z += e * p[d].z; a.w += e * p[d].w;
        }
        short4v o;
        o.x = f2bf(a.x); o.y = f2bf(a.y); o.z = f2bf(a.z); o.w = f2bf(a.w);
        ((short4v*)outp)[(size_t)(nb * 64 + nn) * 4096 + cq] = o;
    }
}

// genb (fp32): bspa[n][o] then btem[R][o], fused in one grid of 160 blocks.
__global__ __launch_bounds__(256)
void k_genb(const float* __restrict__ bp_spa, const float* __restrict__ bp_tem,
            const float* __restrict__ node_eb, const float* __restrict__ time_eb,
            float* __restrict__ bspa, float* __restrict__ btem)
{
    int q = blockIdx.x * 256 + threadIdx.x;   // float4 index
    const float *bp, *emb; float* outp;
    if (q < NN * 32) { bp = bp_spa; emb = node_eb; outp = bspa; }
    else { q -= NN * 32; bp = bp_tem; emb = time_eb; outp = btem; }
    const int n = q >> 5, oq = q & 31;
    float4 a = make_float4(0.f, 0.f, 0.f, 0.f);
    #pragma unroll
    for (int d = 0; d < EMB; ++d) {
        float e = emb[n * EMB + d];
        float4 b = ((const float4*)bp)[d * 32 + oq];
        a.x += e * b.x; a.y += e * b.y; a.z += e * b.z; a.w += e * b.w;
    }
    ((float4*)outp)[q] = a;
}

// ---------------------------------------------------------------------------
// k_spatial (MFMA): h2[R][n][:] = leaky((eb[R][n]@W1+b1) @ Wspa[n] + bspa[n])
// grid (512 n, 12 R-tiles of 64). Wave tile 32x64 (2x2 wave grid).
// Phase1 K=64 mfma; h1 -> LDS bf16 (A-layout); Phase2 K=128 mfma;
// epilogue round-trips LDS for coalesced 16B h2 stores.
// LDS 53.2 KB -> 3 blocks/CU.
// ---------------------------------------------------------------------------
__global__ __launch_bounds__(256)
void k_spatial(const float* __restrict__ eb, const short* __restrict__ w1t,
               const float* __restrict__ b1, const short* __restrict__ wspa,
               const float* __restrict__ bspa, short* __restrict__ h2)
{
    const int n = blockIdx.x, R0 = blockIdx.y * 64;
    const int t = threadIdx.x;
    const int wave = t >> 6, lane = t & 63, quad = lane >> 4, l15 = lane & 15;
    const int m0 = (wave >> 1) * 32, n0 = (wave & 1) * 64;

    __shared__ short sH1[64 * 136];     // h1 / h2-tile, rows x (128+8)
    __shared__ short sU[128 * 136];     // union: {sEb[64][72] + sW1[128][72]} / sWs[128][136]
    __shared__ float sB1[128], sBs[128];
    short* sEb = sU;
    short* sW1 = sU + 64 * 72;
    short* sWs = sU;

    // stage eb 64 rows x 64 k (fp32 -> bf16)
    #pragma unroll
    for (int c = 0; c < 4; ++c) {
        int idx = c * 256 + t;
        int r = idx >> 4, kq = (idx & 15) * 4;
        float4 v = *(const float4*)(eb + ((size_t)(R0 + r) * NN + n) * DIN + kq);
        short4v s;
        s.x = f2bf(v.x); s.y = f2bf(v.y); s.z = f2bf(v.z); s.w = f2bf(v.w);
        *(short4v*)(sEb + r * 72 + kq) = s;
    }
    // stage W1T (8192 bf16)
    #pragma unroll
    for (int c = 0; c < 4; ++c) {
        int idx = c * 256 + t;
        *(bf16x8*)(sW1 + (idx >> 3) * 72 + (idx & 7) * 8) =
            *(const bf16x8*)(w1t + idx * 8);
    }
    if (t < 128) { sB1[t] = b1[t]; sBs[t] = bspa[n * HID + t]; }
    __syncthreads();

    // phase 1: h1 = eb @ W1 (+b1)
    f32x4 acc1[2][4] = {};
    #pragma unroll
    for (int kc = 0; kc < 2; ++kc) {
        bf16x8 a0 = *(const bf16x8*)(sEb + (m0 + l15) * 72 + kc * 32 + quad * 8);
        bf16x8 a1 = *(const bf16x8*)(sEb + (m0 + 16 + l15) * 72 + kc * 32 + quad * 8);
        #pragma unroll
        for (int tc = 0; tc < 4; ++tc) {
            bf16x8 b = *(const bf16x8*)(sW1 + (n0 + tc * 16 + l15) * 72 + kc * 32 + quad * 8);
            acc1[0][tc] = __builtin_amdgcn_mfma_f32_16x16x32_bf16(a0, b, acc1[0][tc], 0, 0, 0);
            acc1[1][tc] = __builtin_amdgcn_mfma_f32_16x16x32_bf16(a1, b, acc1[1][tc], 0, 0, 0);
        }
    }
    #pragma unroll
    for (int tr = 0; tr < 2; ++tr)
        #pragma unroll
        for (int tc = 0; tc < 4; ++tc) {
            int col = n0 + tc * 16 + l15;
            float bb = sB1[col];
            #pragma unroll
            for (int r = 0; r < 4; ++r)
                sH1[(m0 + tr * 16 + quad * 4 + r) * 136 + col] = f2bf(acc1[tr][tc][r] + bb);
        }
    __syncthreads();

    // stage Wspa_t[n] (16384 bf16, contiguous)
    {
        const bf16x8* src = (const bf16x8*)(wspa + (size_t)n * 16384);
        #pragma unroll
        for (int c = 0; c < 8; ++c) {
            int idx = c * 256 + t;
            *(bf16x8*)(sWs + (idx >> 4) * 136 + (idx & 15) * 8) = src[idx];
        }
    }
    __syncthreads();

    // phase 2: h2 = h1 @ Wspa
    f32x4 acc2[2][4] = {};
    #pragma unroll
    for (int kc = 0; kc < 4; ++kc) {
        bf16x8 a0 = *(const bf16x8*)(sH1 + (m0 + l15) * 136 + kc * 32 + quad * 8);
        bf16x8 a1 = *(const bf16x8*)(sH1 + (m0 + 16 + l15) * 136 + kc * 32 + quad * 8);
        #pragma unroll
        for (int tc = 0; tc < 4; ++tc) {
            bf16x8 b = *(const bf16x8*)(sWs + (n0 + tc * 16 + l15) * 136 + kc * 32 + quad * 8);
            acc2[0][tc] = __builtin_amdgcn_mfma_f32_16x16x32_bf16(a0, b, acc2[0][tc], 0, 0, 0);
            acc2[1][tc] = __builtin_amdgcn_mfma_f32_16x16x32_bf16(a1, b, acc2[1][tc], 0, 0, 0);
        }
    }
    __syncthreads();   // everyone done reading sH1
    #pragma unroll
    for (int tr = 0; tr < 2; ++tr)
        #pragma unroll
        for (int tc = 0; tc < 4; ++tc) {
            int col = n0 + tc * 16 + l15;
            float bb = sBs[col];
            #pragma unroll
            for (int r = 0; r < 4; ++r) {
                float v = acc2[tr][tc][r] + bb;
                v = (v >= 0.f) ? v : SLOPE * v;
                sH1[(m0 + tr * 16 + quad * 4 + r) * 136 + col] = f2bf(v);
            }
        }
    __syncthreads();
    #pragma unroll
    for (int c = 0; c < 4; ++c) {
        int idx = c * 256 + t;
        int row = idx >> 4, col = (idx & 15) * 8;
        *(bf16x8*)(h2 + ((size_t)(R0 + row) * NN + n) * HID + col) =
            *(const bf16x8*)(sH1 + row * 136 + col);
    }
}

// ---------------------------------------------------------------------------
// k_temporal (MFMA): out[R][n][:] = leaky(h2[R]@Wtem[R]+btem[R]) @ W3 + b3
// grid 768 (one per R). Wtem_t resident in LDS; 8 chunks of 64 n-rows.
// Wave tile 16x128; W3 epilogue fused with 16-lane shfl reduction.
// LDS 53.8 KB -> 3 blocks/CU (= exactly one full round of 768 blocks).
// ---------------------------------------------------------------------------
__global__ __launch_bounds__(256)
void k_temporal(const short* __restrict__ h2, const short* __restrict__ wtem,
                const float* __restrict__ btem, const float* __restrict__ W3,
                const float* __restrict__ b3, float* __restrict__ out)
{
    const int R = blockIdx.x, t = threadIdx.x;
    const int wave = t >> 6, lane = t & 63, quad = lane >> 4, l15 = lane & 15;
    const int m0 = wave * 16;

    __shared__ short sWt[128 * 136];
    __shared__ short sH2[64 * 136];
    __shared__ float sBt[128], sW3[256];

    {
        const bf16x8* src = (const bf16x8*)(wtem + (size_t)R * 16384);
        #pragma unroll
        for (int c = 0; c < 8; ++c) {
            int idx = c * 256 + t;
            *(bf16x8*)(sWt + (idx >> 4) * 136 + (idx & 15) * 8) = src[idx];
        }
    }
    if (t < 128) sBt[t] = btem[R * HID + t];
    sW3[t] = W3[t];
    const float b30 = b3[0], b31 = b3[1];

    for (int nt = 0; nt < 8; ++nt) {
        __syncthreads();
        const bf16x8* src = (const bf16x8*)(h2 + ((size_t)R * NN + nt * 64) * HID);
        #pragma unroll
        for (int c = 0; c < 4; ++c) {
            int idx = c * 256 + t;
            *(bf16x8*)(sH2 + (idx >> 4) * 136 + (idx & 15) * 8) = src[idx];
        }
        __syncthreads();

        f32x4 acc[8] = {};
        #pragma unroll
        for (int kc = 0; kc < 4; ++kc) {
            bf16x8 a = *(const bf16x8*)(sH2 + (m0 + l15) * 136 + kc * 32 + quad * 8);
            #pragma unroll
            for (int tc = 0; tc < 8; ++tc) {
                bf16x8 b = *(const bf16x8*)(sWt + (tc * 16 + l15) * 136 + kc * 32 + quad * 8);
                acc[tc] = __builtin_amdgcn_mfma_f32_16x16x32_bf16(a, b, acc[tc], 0, 0, 0);
            }
        }
        float pl[4][2] = {};
        #pragma unroll
        for (int tc = 0; tc < 8; ++tc) {
            int o = tc * 16 + l15;
            float bt = sBt[o], w0 = sW3[2 * o], w1 = sW3[2 * o + 1];
            #pragma unroll
            for (int r = 0; r < 4; ++r) {
                float v = acc[tc][r] + bt;
                v = (v >= 0.f) ? v : SLOPE * v;
                pl[r][0] += v * w0;
                pl[r][1] += v * w1;
            }
        }
        #pragma unroll
        for (int m = 1; m <= 8; m <<= 1)
            #pragma unroll
            for (int r = 0; r < 4; ++r) {
                pl[r][0] += __shfl_xor(pl[r][0], m);
                pl[r][1] += __shfl_xor(pl[r][1], m);
            }
        if (l15 == 0) {
            #pragma unroll
            for (int r = 0; r < 4; ++r) {
                int nrow = nt * 64 + m0 + quad * 4 + r;
                *(float2*)(out + ((size_t)R * NN + nrow) * 2) =
                    make_float2(pl[r][0] + b30, pl[r][1] + b31);
            }
        }
    }
}

extern "C" void kernel_launch(void* const* d_in, const int* in_sizes, int n_in,
                              void* d_out, int out_size, void* d_ws, size_t ws_size,
                              hipStream_t stream) {
    const float* eb        = (const float*)d_in[0];
    const float* time_eb   = (const float*)d_in[1];
    const float* node_eb   = (const float*)d_in[2];
    const float* W1        = (const float*)d_in[3];
    const float* b1        = (const float*)d_in[4];
    const float* W3        = (const float*)d_in[5];
    const float* b3        = (const float*)d_in[6];
    const float* pool_spa  = (const float*)d_in[7];
    const float* bpool_spa = (const float*)d_in[8];
    const float* pool_tem  = (const float*)d_in[9];
    const float* bpool_tem = (const float*)d_in[10];
    float* out = (float*)d_out;

    char* ws = (char*)d_ws;
    short* wspa = (short*)(ws + OFF_WSPA);
    short* wtem = (short*)(ws + OFF_WTEM);
    float* bspa = (float*)(ws + OFF_BSPA);
    float* btem = (float*)(ws + OFF_BTEM);
    short* pts  = (short*)(ws + OFF_PTS);
    short* ptt  = (short*)(ws + OFF_PTT);
    short* w1t  = (short*)(ws + OFF_W1T);
    short* h2   = (short*)(ws + OFF_H2);

    k_prep<<<129, 256, 0, stream>>>(pool_spa, pool_tem, W1, pts, ptt, w1t);
    k_genw<<<dim3(16, 20), 256, 0, stream>>>(pts, ptt, node_eb, time_eb, wspa, wtem);
    k_genb<<<160, 256, 0, stream>>>(bpool_spa, bpool_tem, node_eb, time_eb, bspa, btem);
    k_spatial<<<dim3(NN, 12), 256, 0, stream>>>(eb, w1t, b1, wspa, bspa, h2);
    k_temporal<<<BT, 256, 0, stream>>>(h2, wtem, btem, W3, b3, out);
}

// Round 3
// 244.793 us; speedup vs baseline: 3.2888x; 1.0143x over previous
//
#include <hip/hip_runtime.h>
#include <hip/hip_bf16.h>
#include <stdint.h>

// Problem constants
#define BT   768
#define NN   512
#define DIN  64
#define HID  128
#define EMB  16
#define SLOPE 0.01f

typedef __attribute__((ext_vector_type(8))) short bf16x8;   // 8 bf16 (4 VGPRs)
typedef __attribute__((ext_vector_type(4))) float f32x4;    // MFMA C/D frag
typedef __attribute__((ext_vector_type(4))) short short4v;

__device__ __forceinline__ short f2bf(float f) {            // fp32 -> bf16 RNE
    uint32_t u = __float_as_uint(f);
    u += 0x7fff + ((u >> 16) & 1);
    return (short)(u >> 16);
}
__device__ __forceinline__ float bf2f(short s) {
    return __uint_as_float(((uint32_t)(unsigned short)s) << 16);
}

// ---------------- workspace layout (bytes) ----------------
static const size_t OFF_WSPA = 0;          // [512][128 o][128 i] bf16
static const size_t OFF_WTEM = 16777216;   // [768][128][128] bf16
static const size_t OFF_BSPA = 41943040;   // fp32
static const size_t OFF_BTEM = 42205184;   // fp32
static const size_t OFF_PTS  = 42598400;   // pool_spa^T bf16 [d][o][i]
static const size_t OFF_PTT  = 43122688;   // pool_tem^T bf16
static const size_t OFF_W1T  = 43646976;   // W1^T bf16 [o][k]
static const size_t OFF_H2   = 43663360;   // bf16 [R][n][o]

// ---------------------------------------------------------------------------
// k_prep: blocks 0..63 transpose pool_spa -> bf16 [d][o][i]; 64..127 pool_tem;
// block 128 builds W1T; blocks 129..288 compute bspa/btem (fused genb).
// ---------------------------------------------------------------------------
__global__ __launch_bounds__(256)
void k_prep(const float* __restrict__ pool_spa, const float* __restrict__ pool_tem,
            const float* __restrict__ W1,
            const float* __restrict__ bp_spa, const float* __restrict__ bp_tem,
            const float* __restrict__ node_eb, const float* __restrict__ time_eb,
            short* __restrict__ pts, short* __restrict__ ptt,
            short* __restrict__ w1t, float* __restrict__ bspa,
            float* __restrict__ btem)
{
    const int b = blockIdx.x, t = threadIdx.x;
    if (b >= 129) {                                // fused genb
        int q = (b - 129) * 256 + t;               // float4 index
        const float *bp, *emb; float* outp;
        if (q < NN * 32) { bp = bp_spa; emb = node_eb; outp = bspa; }
        else { q -= NN * 32; bp = bp_tem; emb = time_eb; outp = btem; }
        const int n = q >> 5, oq = q & 31;
        float4 a = make_float4(0.f, 0.f, 0.f, 0.f);
        #pragma unroll
        for (int d = 0; d < EMB; ++d) {
            float e = emb[n * EMB + d];
            float4 bv = ((const float4*)bp)[d * 32 + oq];
            a.x += e * bv.x; a.y += e * bv.y; a.z += e * bv.z; a.w += e * bv.w;
        }
        ((float4*)outp)[q] = a;
        return;
    }
    if (b == 128) {
        int o = t >> 1, kh = (t & 1) * 32;
        for (int k = 0; k < 32; ++k)
            w1t[o * 64 + kh + k] = f2bf(W1[(kh + k) * HID + o]);
        return;
    }
    const float* pool = (b < 64) ? pool_spa : pool_tem;
    short* outp = (b < 64) ? pts : ptt;
    const int bb = b & 63;
    const int d = bb >> 2, o0 = (bb & 3) * 32;
    __shared__ short s[32 * 136];
    #pragma unroll
    for (int c = 0; c < 16; ++c) {
        int e = c * 256 + t;
        int i = e >> 5, oo = e & 31;
        s[oo * 136 + i] = f2bf(pool[(d * HID + i) * HID + o0 + oo]);
    }
    __syncthreads();
    #pragma unroll
    for (int c = 0; c < 8; ++c) {
        int e = c * 256 + t;
        int oo = e >> 6, ii = (e & 63) * 2;
        uint32_t lo = (unsigned short)s[oo * 136 + ii];
        uint32_t hi = (unsigned short)s[oo * 136 + ii + 1];
        ((uint32_t*)outp)[((d * HID + o0 + oo) * HID + ii) >> 1] = lo | (hi << 16);
    }
}

// ---------------------------------------------------------------------------
// k_genw: out_t[n][o][i] = sum_d emb[n][d] * pool_t[d][o][i]   (bf16 out)
// ---------------------------------------------------------------------------
__global__ __launch_bounds__(256)
void k_genw(const short* __restrict__ pts, const short* __restrict__ ptt,
            const float* __restrict__ node_eb, const float* __restrict__ time_eb,
            short* __restrict__ wspa, short* __restrict__ wtem)
{
    const int t = threadIdx.x;
    const bool spa = blockIdx.y < 8;
    const int nb = spa ? blockIdx.y : blockIdx.y - 8;
    const short* pool = spa ? pts : ptt;
    const float* emb = spa ? node_eb : time_eb;
    short* outp = spa ? wspa : wtem;
    __shared__ float sEmb[64 * EMB];
    #pragma unroll
    for (int c = 0; c < 4; ++c) {
        int idx = c * 256 + t;
        sEmb[idx] = emb[nb * 64 * EMB + idx];
    }
    __syncthreads();
    const int cq = blockIdx.x * 256 + t;      // group of 4 bf16 cols
    float4 p[EMB];
    #pragma unroll
    for (int d = 0; d < EMB; ++d) {
        short4v v = ((const short4v*)pool)[d * 4096 + cq];
        p[d] = make_float4(bf2f(v.x), bf2f(v.y), bf2f(v.z), bf2f(v.w));
    }
    for (int nn = 0; nn < 64; ++nn) {
        float4 a = make_float4(0.f, 0.f, 0.f, 0.f);
        #pragma unroll
        for (int d = 0; d < EMB; ++d) {
            float e = sEmb[nn * EMB + d];
            a.x += e * p[d].x; a.y += e * p[d].y;
            a.z += e * p[d].z; a.w += e * p[d].w;
        }
        short4v o;
        o.x = f2bf(a.x); o.y = f2bf(a.y); o.z = f2bf(a.z); o.w = f2bf(a.w);
        ((short4v*)outp)[(size_t)(nb * 64 + nn) * 4096 + cq] = o;
    }
}

// ---------------------------------------------------------------------------
// k_spatial: h2[R][n][:] = leaky((eb[R][n]@W1+b1) @ Wspa[n] + bspa[n])
// grid (512 n, 12 R-tiles of 64). Wave tile 32x64 (2x2 wave grid).
// Wspa register-prefetched at start (issued AFTER eb/W1 so their vmcnt
// waits don't drain it); biases in registers. LDS 52.2 KB -> 3 blocks/CU.
// No mid-kernel global stalls.
// ---------------------------------------------------------------------------
__global__ __launch_bounds__(256)
void k_spatial(const float* __restrict__ eb, const short* __restrict__ w1t,
               const float* __restrict__ b1, const short* __restrict__ wspa,
               const float* __restrict__ bspa, short* __restrict__ h2)
{
    const int n = blockIdx.x, R0 = blockIdx.y * 64;
    const int t = threadIdx.x;
    const int wave = t >> 6, lane = t & 63, quad = lane >> 4, l15 = lane & 15;
    const int m0 = (wave >> 1) * 32, n0 = (wave & 1) * 64;

    __shared__ short sH1[64 * 136];     // h1 / h2-tile
    __shared__ short sU[128 * 136];     // union: {sEb[64][72]+sW1[128][72]} / sWs[128][136]
    short* sEb = sU;
    short* sW1 = sU + 64 * 72;
    short* sWs = sU;

    // ---- issue eb (fp32) and W1T loads first ----
    float4 ev[4];
    #pragma unroll
    for (int c = 0; c < 4; ++c) {
        int idx = c * 256 + t;
        int r = idx >> 4, kq = (idx & 15) * 4;
        ev[c] = *(const float4*)(eb + ((size_t)(R0 + r) * NN + n) * DIN + kq);
    }
    bf16x8 w1v[4];
    #pragma unroll
    for (int c = 0; c < 4; ++c) w1v[c] = ((const bf16x8*)w1t)[c * 256 + t];
    float b1r[4], bsr[4];
    #pragma unroll
    for (int tc = 0; tc < 4; ++tc) {
        int col = n0 + tc * 16 + l15;
        b1r[tc] = b1[col];
        bsr[tc] = bspa[n * HID + col];
    }
    // ---- prefetch Wspa[n] into registers (consumed after phase 1) ----
    bf16x8 wreg[8];
    {
        const bf16x8* src = (const bf16x8*)(wspa + (size_t)n * 16384);
        #pragma unroll
        for (int c = 0; c < 8; ++c) wreg[c] = src[c * 256 + t];
    }
    // ---- stage eb (cvt bf16) and W1T to LDS ----
    #pragma unroll
    for (int c = 0; c < 4; ++c) {
        int idx = c * 256 + t;
        int r = idx >> 4, kq = (idx & 15) * 4;
        short4v s;
        s.x = f2bf(ev[c].x); s.y = f2bf(ev[c].y);
        s.z = f2bf(ev[c].z); s.w = f2bf(ev[c].w);
        *(short4v*)(sEb + r * 72 + kq) = s;
    }
    #pragma unroll
    for (int c = 0; c < 4; ++c) {
        int idx = c * 256 + t;
        *(bf16x8*)(sW1 + (idx >> 3) * 72 + (idx & 7) * 8) = w1v[c];
    }
    __syncthreads();

    // ---- phase 1: h1 = eb @ W1 (+b1) ----
    f32x4 acc1[2][4] = {};
    #pragma unroll
    for (int kc = 0; kc < 2; ++kc) {
        bf16x8 a0 = *(const bf16x8*)(sEb + (m0 + l15) * 72 + kc * 32 + quad * 8);
        bf16x8 a1 = *(const bf16x8*)(sEb + (m0 + 16 + l15) * 72 + kc * 32 + quad * 8);
        #pragma unroll
        for (int tc = 0; tc < 4; ++tc) {
            bf16x8 b = *(const bf16x8*)(sW1 + (n0 + tc * 16 + l15) * 72 + kc * 32 + quad * 8);
            acc1[0][tc] = __builtin_amdgcn_mfma_f32_16x16x32_bf16(a0, b, acc1[0][tc], 0, 0, 0);
            acc1[1][tc] = __builtin_amdgcn_mfma_f32_16x16x32_bf16(a1, b, acc1[1][tc], 0, 0, 0);
        }
    }
    #pragma unroll
    for (int tr = 0; tr < 2; ++tr)
        #pragma unroll
        for (int tc = 0; tc < 4; ++tc) {
            int col = n0 + tc * 16 + l15;
            #pragma unroll
            for (int r = 0; r < 4; ++r)
                sH1[(m0 + tr * 16 + quad * 4 + r) * 136 + col] = f2bf(acc1[tr][tc][r] + b1r[tc]);
        }
    __syncthreads();                       // all phase-1 reads of sU done

    // ---- dump prefetched Wspa regs into LDS (no global wait here) ----
    #pragma unroll
    for (int c = 0; c < 8; ++c) {
        int idx = c * 256 + t;
        *(bf16x8*)(sWs + (idx >> 4) * 136 + (idx & 15) * 8) = wreg[c];
    }
    __syncthreads();

    // ---- phase 2: h2 = h1 @ Wspa ----
    f32x4 acc2[2][4] = {};
    #pragma unroll
    for (int kc = 0; kc < 4; ++kc) {
        bf16x8 a0 = *(const bf16x8*)(sH1 + (m0 + l15) * 136 + kc * 32 + quad * 8);
        bf16x8 a1 = *(const bf16x8*)(sH1 + (m0 + 16 + l15) * 136 + kc * 32 + quad * 8);
        #pragma unroll
        for (int tc = 0; tc < 4; ++tc) {
            bf16x8 b = *(const bf16x8*)(sWs + (n0 + tc * 16 + l15) * 136 + kc * 32 + quad * 8);
            acc2[0][tc] = __builtin_amdgcn_mfma_f32_16x16x32_bf16(a0, b, acc2[0][tc], 0, 0, 0);
            acc2[1][tc] = __builtin_amdgcn_mfma_f32_16x16x32_bf16(a1, b, acc2[1][tc], 0, 0, 0);
        }
    }
    __syncthreads();                       // everyone done reading sH1
    #pragma unroll
    for (int tr = 0; tr < 2; ++tr)
        #pragma unroll
        for (int tc = 0; tc < 4; ++tc) {
            int col = n0 + tc * 16 + l15;
            #pragma unroll
            for (int r = 0; r < 4; ++r) {
                float v = acc2[tr][tc][r] + bsr[tc];
                v = (v >= 0.f) ? v : SLOPE * v;
                sH1[(m0 + tr * 16 + quad * 4 + r) * 136 + col] = f2bf(v);
            }
        }
    __syncthreads();
    #pragma unroll
    for (int c = 0; c < 4; ++c) {
        int idx = c * 256 + t;
        int row = idx >> 4, col = (idx & 15) * 8;
        *(bf16x8*)(h2 + ((size_t)(R0 + row) * NN + n) * HID + col) =
            *(const bf16x8*)(sH1 + row * 136 + col);
    }
}

// ---------------------------------------------------------------------------
// k_temporal: out[R][n][:] = leaky(h2[R]@Wtem[R]+btem[R]) @ W3 + b3
// grid (768 R, 2 n-halves of 256). Wtem resident in LDS; 4 chunks of 64 rows
// with register double-buffered h2 prefetch. Bias/W3 in registers.
// LDS 52.2 KB -> 3 blocks/CU; 1536 blocks.
// ---------------------------------------------------------------------------
__global__ __launch_bounds__(256)
void k_temporal(const short* __restrict__ h2, const short* __restrict__ wtem,
                const float* __restrict__ btem, const float* __restrict__ W3,
                const float* __restrict__ b3, float* __restrict__ out)
{
    const int R = blockIdx.x, nbase = blockIdx.y * 256;
    const int t = threadIdx.x;
    const int wave = t >> 6, lane = t & 63, quad = lane >> 4, l15 = lane & 15;
    const int m0 = wave * 16;

    __shared__ short sWt[128 * 136];
    __shared__ short sH2[64 * 136];

    // issue Wtem loads, then chunk-0 loads, then scalar-ish bias/W3 loads
    bf16x8 wv[8];
    {
        const bf16x8* src = (const bf16x8*)(wtem + (size_t)R * 16384);
        #pragma unroll
        for (int c = 0; c < 8; ++c) wv[c] = src[c * 256 + t];
    }
    bf16x8 hreg[4];
    {
        const bf16x8* src = (const bf16x8*)(h2 + ((size_t)R * NN + nbase) * HID);
        #pragma unroll
        for (int c = 0; c < 4; ++c) hreg[c] = src[c * 256 + t];
    }
    float btr[8], w3r0[8], w3r1[8];
    #pragma unroll
    for (int tc = 0; tc < 8; ++tc) {
        int o = tc * 16 + l15;
        btr[tc] = btem[R * HID + o];
        w3r0[tc] = W3[2 * o]; w3r1[tc] = W3[2 * o + 1];
    }
    const float b30 = b3[0], b31 = b3[1];

    #pragma unroll
    for (int c = 0; c < 8; ++c) {
        int idx = c * 256 + t;
        *(bf16x8*)(sWt + (idx >> 4) * 136 + (idx & 15) * 8) = wv[c];
    }
    #pragma unroll
    for (int c = 0; c < 4; ++c) {
        int idx = c * 256 + t;
        *(bf16x8*)(sH2 + (idx >> 4) * 136 + (idx & 15) * 8) = hreg[c];
    }
    __syncthreads();

    for (int nt = 0; nt < 4; ++nt) {
        if (nt < 3) {                       // prefetch next chunk (no wait)
            const bf16x8* src = (const bf16x8*)(h2 + ((size_t)R * NN + nbase + (nt + 1) * 64) * HID);
            #pragma unroll
            for (int c = 0; c < 4; ++c) hreg[c] = src[c * 256 + t];
        }
        f32x4 acc[8] = {};
        #pragma unroll
        for (int kc = 0; kc < 4; ++kc) {
            bf16x8 a = *(const bf16x8*)(sH2 + (m0 + l15) * 136 + kc * 32 + quad * 8);
            #pragma unroll
            for (int tc = 0; tc < 8; ++tc) {
                bf16x8 b = *(const bf16x8*)(sWt + (tc * 16 + l15) * 136 + kc * 32 + quad * 8);
                acc[tc] = __builtin_amdgcn_mfma_f32_16x16x32_bf16(a, b, acc[tc], 0, 0, 0);
            }
        }
        float pl[4][2] = {};
        #pragma unroll
        for (int tc = 0; tc < 8; ++tc) {
            #pragma unroll
            for (int r = 0; r < 4; ++r) {
                float v = acc[tc][r] + btr[tc];
                v = (v >= 0.f) ? v : SLOPE * v;
                pl[r][0] += v * w3r0[tc];
                pl[r][1] += v * w3r1[tc];
            }
        }
        #pragma unroll
        for (int m = 1; m <= 8; m <<= 1)
            #pragma unroll
            for (int r = 0; r < 4; ++r) {
                pl[r][0] += __shfl_xor(pl[r][0], m);
                pl[r][1] += __shfl_xor(pl[r][1], m);
            }
        if (l15 == 0) {
            #pragma unroll
            for (int r = 0; r < 4; ++r) {
                int nrow = nbase + nt * 64 + m0 + quad * 4 + r;
                *(float2*)(out + ((size_t)R * NN + nrow) * 2) =
                    make_float2(pl[r][0] + b30, pl[r][1] + b31);
            }
        }
        __syncthreads();                    // sH2 reads done
        if (nt < 3) {
            #pragma unroll
            for (int c = 0; c < 4; ++c) {
                int idx = c * 256 + t;
                *(bf16x8*)(sH2 + (idx >> 4) * 136 + (idx & 15) * 8) = hreg[c];
            }
            __syncthreads();
        }
    }
}

extern "C" void kernel_launch(void* const* d_in, const int* in_sizes, int n_in,
                              void* d_out, int out_size, void* d_ws, size_t ws_size,
                              hipStream_t stream) {
    const float* eb        = (const float*)d_in[0];
    const float* time_eb   = (const float*)d_in[1];
    const float* node_eb   = (const float*)d_in[2];
    const float* W1        = (const float*)d_in[3];
    const float* b1        = (const float*)d_in[4];
    const float* W3        = (const float*)d_in[5];
    const float* b3        = (const float*)d_in[6];
    const float* pool_spa  = (const float*)d_in[7];
    const float* bpool_spa = (const float*)d_in[8];
    const float* pool_tem  = (const float*)d_in[9];
    const float* bpool_tem = (const float*)d_in[10];
    float* out = (float*)d_out;

    char* ws = (char*)d_ws;
    short* wspa = (short*)(ws + OFF_WSPA);
    short* wtem = (short*)(ws + OFF_WTEM);
    float* bspa = (float*)(ws + OFF_BSPA);
    float* btem = (float*)(ws + OFF_BTEM);
    short* pts  = (short*)(ws + OFF_PTS);
    short* ptt  = (short*)(ws + OFF_PTT);
    short* w1t  = (short*)(ws + OFF_W1T);
    short* h2   = (short*)(ws + OFF_H2);

    k_prep<<<289, 256, 0, stream>>>(pool_spa, pool_tem, W1, bpool_spa, bpool_tem,
                                    node_eb, time_eb, pts, ptt, w1t, bspa, btem);
    k_genw<<<dim3(16, 20), 256, 0, stream>>>(pts, ptt, node_eb, time_eb, wspa, wtem);
    k_spatial<<<dim3(NN, 12), 256, 0, stream>>>(eb, w1t, b1, wspa, bspa, h2);
    k_temporal<<<dim3(BT, 2), 256, 0, stream>>>(h2, wtem, btem, W3, b3, out);
}